// Round 1
// 299.707 us; speedup vs baseline: 1.0848x; 1.0848x over previous
//
#include <hip/hip_runtime.h>

typedef unsigned short u16;
typedef unsigned int u32;

typedef __attribute__((ext_vector_type(8))) short short8v;  // 8 bf16 (4 VGPRs)
typedef __attribute__((ext_vector_type(4))) float float4v;  // 4 f32 acc

__device__ __forceinline__ float bf2f(u16 u) {
    return __uint_as_float(((u32)u) << 16);
}
__device__ __forceinline__ u16 f2bf(float f) {
    u32 u = __float_as_uint(f);
    u32 r = (u + 0x7fffu + ((u >> 16) & 1u)) >> 16;
    return (u16)r;
}
__device__ __forceinline__ float ldf(const void* p, int i, int isf32) {
    return isf32 ? ((const float*)p)[i] : bf2f(((const u16*)p)[i]);
}

// ---- canonical f32 param block offsets (in floats) ----
#define P_W1   0        // 128x64
#define P_W2   8192     // 64x64
#define P_B1   12288    // 64
#define P_B2   12352    // 64
#define P_A1W  12416    // 144
#define P_A1B  12560    // 1
#define P_T1W  12561    // 16
#define P_T1B  12577    // 16
#define P_A2W  12593    // 144
#define P_A2B  12737    // 1
#define P_T2W  12738    // 16
#define P_T2B  12754    // 16
#define P_CLSW 12770    // 128 (64x2)
#define P_CLSB 12898    // 2
#define P_TOT  12900

#define CH   4096       // edges per sort chunk
#define NCHB 256        // padded bucket count; bucket = dst>>9 (<=195)
#define CAP  128        // aggregate per-node LDS cache (max observed deg ~50)

// W-fragment array sizes (u16 elements): (K/32) ksteps * 4 coltiles * 64 lanes * 8
#define W1F_ELEMS 16384   // K=128
#define W2F_ELEMS 8192    // K=64

// ---------------------------------------------------------------------------
// Detect f32 vs bf16 storage of float tensors (round-1 notes).
// ---------------------------------------------------------------------------
__global__ __launch_bounds__(256) void detect_dtype(
    const u32* __restrict__ xw, int nwords, int* __restrict__ flag)
{
    __shared__ int sbad;
    if (threadIdx.x == 0) sbad = 0;
    __syncthreads();
    int bad = 0;
    for (int i = threadIdx.x; i < nwords; i += 256) {
        u32 w = xw[i];
        int ea = (w >> 7) & 0xff;
        if (ea >= 0xF0) bad = 1;
    }
    if (bad) sbad = 1;
    __syncthreads();
    if (threadIdx.x == 0) flag[0] = sbad;
}

// ---------------------------------------------------------------------------
// Convert all small parameter tensors into one f32 param block.
// ---------------------------------------------------------------------------
__global__ __launch_bounds__(256) void prep_params(
    const void* l1w, const void* l1b, const void* a1w, const void* a1b,
    const void* t1w, const void* t1b, const void* l2w, const void* l2b,
    const void* a2w, const void* a2b, const void* t2w, const void* t2b,
    const void* clsw, const void* clsb,
    const int* __restrict__ flag, float* __restrict__ P)
{
    const int f = flag[0];
    const int t = blockIdx.x * 256 + threadIdx.x;
    const int stride = gridDim.x * 256;
#define SEG(src, off, cnt) for (int i = t; i < (cnt); i += stride) P[(off) + i] = ldf(src, i, f)
    SEG(l1w, P_W1, 8192);
    SEG(l2w, P_W2, 4096);
    SEG(l1b, P_B1, 64);
    SEG(l2b, P_B2, 64);
    SEG(a1w, P_A1W, 144);
    SEG(a1b, P_A1B, 1);
    SEG(t1w, P_T1W, 16);
    SEG(t1b, P_T1B, 16);
    SEG(a2w, P_A2W, 144);
    SEG(a2b, P_A2B, 1);
    SEG(t2w, P_T2W, 16);
    SEG(t2b, P_T2B, 16);
    SEG(clsw, P_CLSW, 128);
    SEG(clsb, P_CLSB, 2);
#undef SEG
}

// ---------------------------------------------------------------------------
// Pack W1/W2 into MFMA B-fragment order as bf16 hi/lo pairs.
// B-frag for mfma_f32_16x16x32_bf16: lane l holds B[k][col] with
// col = ct*16 + (l&15), k = ks*32 + (l>>4)*8 + j  (j = 0..7).
// Memory: idx = (((ks*4 + ct)*64 + l)*8 + j) -> wave loads one uint4/lane.
// ---------------------------------------------------------------------------
__global__ __launch_bounds__(256) void prep_wfrags(
    const float* __restrict__ P,
    u16* __restrict__ w1h, u16* __restrict__ w1l,
    u16* __restrict__ w2h, u16* __restrict__ w2l)
{
    int e = blockIdx.x * 256 + threadIdx.x;   // 0 .. 24575
    if (e >= W1F_ELEMS + W2F_ELEMS) return;
    int idx, woff;
    u16 *dh, *dl;
    if (e < W1F_ELEMS) { idx = e; woff = P_W1; dh = w1h; dl = w1l; }
    else { idx = e - W1F_ELEMS; woff = P_W2; dh = w2h; dl = w2l; }
    int j = idx & 7;
    int l = (idx >> 3) & 63;
    int ctks = idx >> 9;
    int ct = ctks & 3;
    int ks = ctks >> 2;
    int k = ks * 32 + (l >> 4) * 8 + j;
    int col = ct * 16 + (l & 15);
    float wv = P[woff + k * 64 + col];
    u16 hh = f2bf(wv);
    dh[idx] = hh;
    dl[idx] = f2bf(wv - bf2f(hh));
}

// ---------------------------------------------------------------------------
// Node transform via MFMA: h = x @ W + b (bf16x3 split for f32 accuracy),
// packed bf16 output; fused si/sj. No LDS, no block sync.
// Block = 256 thr = 4 waves; each wave computes a 16-row x 64-col tile.
// XMODE: 0 = runtime flag (f32/bf16 x), 2 = bf16 packed input (layer 2).
// ---------------------------------------------------------------------------
template<int K, int XMODE>
__global__ __launch_bounds__(256) void node_gemm_mfma(
    const void* __restrict__ xin, const float* __restrict__ P,
    int BOFF, int AOFF, const int* __restrict__ flag,
    const u16* __restrict__ wfh, const u16* __restrict__ wfl,
    u32* __restrict__ houtb, float* __restrict__ si, float* __restrict__ sj,
    int nnodes)
{
    const int l = threadIdx.x & 63;
    const int w = threadIdx.x >> 6;
    const int cl = l & 15;          // col-in-tile / A-row lane
    const int cg = l >> 4;          // k-group (loads) / row-group (C)
    const int rowbase = blockIdx.x * 64 + w * 16;
    const bool xf32 = (XMODE == 0) ? (flag[0] != 0) : false;

    const int arow = rowbase + cl;                 // row this lane loads for A
    const int arc = (arow < nnodes) ? arow : 0;    // clamp (stores are guarded)
    const int kb = cg * 8;                         // lane k-offset within 32

    const u16* xb = (const u16*)xin;
    const float* xf = (const float*)xin;
    const short8v* bhp = (const short8v*)wfh;
    const short8v* blp = (const short8v*)wfl;

    float4v acc[4];
    #pragma unroll
    for (int ct = 0; ct < 4; ++ct) acc[ct] = (float4v){0.f, 0.f, 0.f, 0.f};

    #pragma unroll
    for (int ks = 0; ks < K / 32; ++ks) {
        short8v ah, al_;
        bool hasl = false;
        if (XMODE == 2 || !xf32) {
            ah = *(const short8v*)&xb[(size_t)arc * K + ks * 32 + kb];
            al_ = (short8v){0, 0, 0, 0, 0, 0, 0, 0};
        } else {
            float4 v0 = *(const float4*)&xf[(size_t)arc * K + ks * 32 + kb];
            float4 v1 = *(const float4*)&xf[(size_t)arc * K + ks * 32 + kb + 4];
            float fv[8] = { v0.x, v0.y, v0.z, v0.w, v1.x, v1.y, v1.z, v1.w };
            #pragma unroll
            for (int j = 0; j < 8; ++j) {
                u16 hh = f2bf(fv[j]);
                ah[j] = (short)hh;
                al_[j] = (short)f2bf(fv[j] - bf2f(hh));
            }
            hasl = true;
        }
        #pragma unroll
        for (int ct = 0; ct < 4; ++ct) {
            short8v bh = bhp[(ks * 4 + ct) * 64 + l];
            short8v bl = blp[(ks * 4 + ct) * 64 + l];
            acc[ct] = __builtin_amdgcn_mfma_f32_16x16x32_bf16(ah, bh, acc[ct], 0, 0, 0);
            acc[ct] = __builtin_amdgcn_mfma_f32_16x16x32_bf16(ah, bl, acc[ct], 0, 0, 0);
            if (hasl)
                acc[ct] = __builtin_amdgcn_mfma_f32_16x16x32_bf16(al_, bh, acc[ct], 0, 0, 0);
        }
    }

    // C layout: lane l holds col = ct*16 + (l&15), row = (l>>4)*4 + r.
    #pragma unroll
    for (int r = 0; r < 4; ++r) {
        int node = rowbase + cg * 4 + r;
        float aiv = 0.f, ajv = 0.f;
        u16 hs[4];
        #pragma unroll
        for (int ct = 0; ct < 4; ++ct) {
            float v = acc[ct][r] + P[BOFF + ct * 16 + cl];
            aiv = fmaf(v, P[AOFF + ct * 16 + cl], aiv);
            ajv = fmaf(v, P[AOFF + 64 + ct * 16 + cl], ajv);
            hs[ct] = f2bf(v);
        }
        #pragma unroll
        for (int o = 1; o < 16; o <<= 1) {
            aiv += __shfl_xor(aiv, o);
            ajv += __shfl_xor(ajv, o);
        }
        if (node < nnodes) {
            u16* hp = (u16*)houtb + (size_t)node * 64 + cl;
            hp[0] = hs[0]; hp[16] = hs[1]; hp[32] = hs[2]; hp[48] = hs[3];
            if (cl == 0) { si[node] = aiv; sj[node] = ajv; }
        }
    }
}

// ---------------------------------------------------------------------------
// Counting sort pass 1: per-chunk bucket histogram (bucket = dst>>9).
// ---------------------------------------------------------------------------
__global__ __launch_bounds__(256) void count_chunks(
    const int* __restrict__ eid, int* __restrict__ chunkhist, int E)
{
    __shared__ int hist[NCHB];
    const int t = threadIdx.x, c = blockIdx.x;
    hist[t] = 0;
    __syncthreads();
    const int base = c * CH;
    #pragma unroll
    for (int i = 0; i < CH / 256; ++i) {
        int e = base + t + i * 256;
        if (e < E) atomicAdd(&hist[eid[e] >> 9], 1);
    }
    __syncthreads();
    chunkhist[c * NCHB + t] = hist[t];
}

// ---------------------------------------------------------------------------
// Scan stage A: one block per bucket; Hillis-Steele over chunk entries.
// ---------------------------------------------------------------------------
__global__ __launch_bounds__(256) void scan_chunks(
    int* __restrict__ chunkhist, int* __restrict__ buckettot, int nchunks)
{
    __shared__ int s[512];
    const int b = blockIdx.x, t = threadIdx.x;
    int v0 = (t < nchunks) ? chunkhist[(size_t)t * NCHB + b] : 0;
    int v1 = (t + 256 < nchunks) ? chunkhist[(size_t)(t + 256) * NCHB + b] : 0;
    s[t] = v0; s[t + 256] = v1;
    __syncthreads();
    for (int off = 1; off < 512; off <<= 1) {
        int x0 = (t >= off) ? s[t - off] : 0;
        int x1 = s[t + 256 - off];
        __syncthreads();
        s[t] += x0; s[t + 256] += x1;
        __syncthreads();
    }
    if (t < nchunks) chunkhist[(size_t)t * NCHB + b] = s[t] - v0;
    if (t + 256 < nchunks) chunkhist[(size_t)(t + 256) * NCHB + b] = s[t + 256] - v1;
    if (t == 255) buckettot[b] = s[511];
}

// ---------------------------------------------------------------------------
// Scan stage B: 1 tiny block. Exclusive scan of bucket totals.
// ---------------------------------------------------------------------------
__global__ __launch_bounds__(256) void bucket_start_scan(
    const int* __restrict__ buckettot, int* __restrict__ bucketstart,
    int* __restrict__ offs, int N)
{
    __shared__ int s[NCHB];
    const int b = threadIdx.x;
    int v = buckettot[b];
    s[b] = v;
    __syncthreads();
    for (int off = 1; off < NCHB; off <<= 1) {
        int x = (b >= off) ? s[b - off] : 0;
        __syncthreads();
        s[b] += x;
        __syncthreads();
    }
    bucketstart[b] = s[b] - v;
    if (b == NCHB - 1) { bucketstart[NCHB] = s[b]; offs[N] = s[b]; }
}

// ---------------------------------------------------------------------------
// Counting sort pass 2: sort each chunk in LDS, coalesced flush to the
// bucket-sorted staging array. Payload (src | ldst<<17, t_bits).
// ---------------------------------------------------------------------------
__global__ __launch_bounds__(256) void place_chunks(
    const int* __restrict__ ei, const void* __restrict__ et,
    const int* __restrict__ flag, const int* __restrict__ chunkhist,
    const int* __restrict__ bucketstart, int2* __restrict__ staging, int E)
{
    __shared__ int2 sorted[CH];            // 32 KB
    __shared__ unsigned char bno[CH];      // 4 KB
    __shared__ int hist[NCHB], lstart[NCHB], cur[NCHB], gb[NCHB];
    const int t = threadIdx.x, c = blockIdx.x;
    const int base = c * CH;
    const int f = flag[0];
    hist[t] = 0;
    gb[t] = bucketstart[t] + chunkhist[c * NCHB + t];
    __syncthreads();
    #pragma unroll
    for (int i = 0; i < CH / 256; ++i) {
        int e = base + t + i * 256;
        if (e < E) atomicAdd(&hist[ei[E + e] >> 9], 1);
    }
    __syncthreads();
    int v = hist[t];
    lstart[t] = v;
    __syncthreads();
    for (int off = 1; off < NCHB; off <<= 1) {
        int x = (t >= off) ? lstart[t - off] : 0;
        __syncthreads();
        lstart[t] += x;
        __syncthreads();
    }
    int ex = lstart[t] - v;   // exclusive local start
    __syncthreads();
    lstart[t] = ex;
    cur[t] = ex;
    __syncthreads();
    #pragma unroll
    for (int i = 0; i < CH / 256; ++i) {
        int e = base + t + i * 256;
        if (e < E) {
            int s_ = ei[e], d = ei[E + e];
            float tt = ldf(et, e, f);
            int b = d >> 9;
            int p = atomicAdd(&cur[b], 1);
            sorted[p] = make_int2(s_ | ((d & 511) << 17), __float_as_int(tt));
            bno[p] = (unsigned char)b;
        }
    }
    __syncthreads();
    const int cnt_tot = min(CH, E - base);
    for (int idx = t; idx < cnt_tot; idx += 256) {
        int b = bno[idx];
        staging[gb[b] + (idx - lstart[b])] = sorted[idx];
    }
}

// ---------------------------------------------------------------------------
// Bin within bucket (low VGPR): per-node LDS histogram + scan -> offs;
// place (src, t) into node-sorted csrA.
// ---------------------------------------------------------------------------
__global__ __launch_bounds__(256) void bin_edges(
    const int2* __restrict__ staging, const int* __restrict__ bucketstart,
    int* __restrict__ offs, int2* __restrict__ csrA, int N)
{
    __shared__ int cnt[512], loc[512];
    const int b = blockIdx.x, t = threadIdx.x;
    const int beg = bucketstart[b], end = bucketstart[b + 1];
    const int nstart = b << 9;
    cnt[t] = 0; cnt[t + 256] = 0;
    __syncthreads();
    for (int i = beg + t; i < end; i += 256)
        atomicAdd(&cnt[(((u32)staging[i].x) >> 17) & 511], 1);
    __syncthreads();
    int v0 = cnt[t], v1 = cnt[t + 256];
    loc[t] = v0; loc[t + 256] = v1;
    __syncthreads();
    for (int off = 1; off < 512; off <<= 1) {
        int x0 = (t >= off) ? loc[t - off] : 0;
        int x1 = loc[t + 256 - off];
        __syncthreads();
        loc[t] += x0; loc[t + 256] += x1;
        __syncthreads();
    }
    int cur0 = beg + loc[t] - v0;
    int cur1 = beg + loc[t + 256] - v1;
    if (nstart + t < N) offs[nstart + t] = cur0;
    if (nstart + t + 256 < N) offs[nstart + t + 256] = cur1;
    cnt[t] = cur0; cnt[t + 256] = cur1;
    __syncthreads();
    for (int i = beg + t; i < end; i += 256) {
        int2 e = staging[i];
        int slot = atomicAdd(&cnt[(((u32)e.x) >> 17) & 511], 1);
        csrA[slot] = make_int2(e.x & 0x1ffff, e.y);
    }
}

// ---------------------------------------------------------------------------
// Temporal pass: coalesced stream over the node-sorted CSR. csrA -> (src,
// td1+b1) in place, csrB = (src, td2+b2). Keeps all sin out of the hot
// aggregates without bloating bin_edges' registers (round-10 lesson).
// ---------------------------------------------------------------------------
__global__ __launch_bounds__(256) void temporal_pass(
    int2* __restrict__ csrA, int2* __restrict__ csrB,
    const float* __restrict__ P, int E)
{
    int i = blockIdx.x * 256 + threadIdx.x;
    if (i >= E) return;
    int2 e = csrA[i];
    float tt = __int_as_float(e.y);
    float td1 = P[P_A1B], td2 = P[P_A2B];
    #pragma unroll
    for (int k = 0; k < 16; ++k) {
        td1 += __sinf(fmaf(tt, P[P_T1W + k], P[P_T1B + k])) * P[P_A1W + 128 + k];
        td2 += __sinf(fmaf(tt, P[P_T2W + k], P[P_T2B + k])) * P[P_A2W + 128 + k];
    }
    csrA[i] = make_int2(e.x, __float_as_int(td1));
    csrB[i] = make_int2(e.x, __float_as_int(td2));
}

// ---------------------------------------------------------------------------
// Aggregate: TWO nodes per wave (half-wave = 32 lanes owns one node).
// Single alpha pass (bounded alpha, clamp 80 — softmax ratio unchanged).
// LDS cache (src, e) padded to a multiple of 4 with zero-weight entries so
// phase B is ONLY the 4-loads-in-flight group loop (no tail). No block sync
// (cache is wave-private). Global fallback for deg > CAP (never fires).
// ---------------------------------------------------------------------------
template<int MODE>
__global__ __launch_bounds__(256) void aggregate(
    const int* __restrict__ offs, const int2* __restrict__ csr2,
    const u32* __restrict__ hb,
    const float* __restrict__ si, const float* __restrict__ sjv,
    const float* __restrict__ P,
    u32* __restrict__ houtb, void* __restrict__ outp,
    const int* __restrict__ flag, int n)
{
    __shared__ int2 cache[4][2][CAP];
    const int wave = threadIdx.x >> 6;
    const int lane = threadIdx.x & 63;
    const int half = lane >> 5;          // which node of the pair
    const int hl = lane & 31;            // lane within half
    const int node = blockIdx.x * 8 + wave * 2 + half;
    const bool active = node < n;
    int beg = 0, end = 0;
    if (active) { beg = offs[node]; end = offs[node + 1]; }
    const int deg = end - beg;
    int2* cw = cache[wave][half];
    const float sii = active ? si[node] : 0.f;

    // phase A: e = exp(leaky(si+sj+td)) once per edge; cache; ssum
    float ssum = 0.f;
    for (int idx = hl; idx < deg; idx += 32) {
        int2 st = csr2[beg + idx];
        float a = sii + sjv[st.x] + __int_as_float(st.y);
        a = (a > 0.f) ? a : 0.01f * a;
        float e = __expf(fminf(a, 80.f));
        if (idx < CAP) cw[idx] = make_int2(st.x, __float_as_int(e));
        ssum += e;
    }
    #pragma unroll
    for (int o = 16; o > 0; o >>= 1) ssum += __shfl_xor(ssum, o);

    // pad cache to a multiple of 4 with zero-weight entries
    const int degc = min(deg, CAP);
    const int degpad = (degc + 3) & ~3;
    if (hl < degpad - degc) cw[degc + hl] = make_int2(0, 0);

    // phase B: 32 lanes per edge row (u32 = 2 bf16 feats); 4 loads in flight
    float ax = 0.f, ay = 0.f;
    for (int j0 = 0; j0 < degpad; j0 += 4) {
        int2 s0 = cw[j0 + 0];
        int2 s1 = cw[j0 + 1];
        int2 s2 = cw[j0 + 2];
        int2 s3 = cw[j0 + 3];
        u32 p0 = hb[s0.x * 32 + hl];
        u32 p1 = hb[s1.x * 32 + hl];
        u32 p2 = hb[s2.x * 32 + hl];
        u32 p3 = hb[s3.x * 32 + hl];
        float e0 = __int_as_float(s0.y);
        float e1 = __int_as_float(s1.y);
        float e2 = __int_as_float(s2.y);
        float e3 = __int_as_float(s3.y);
        ax = fmaf(e0, __uint_as_float(p0 << 16), ax);
        ay = fmaf(e0, __uint_as_float(p0 & 0xffff0000u), ay);
        ax = fmaf(e1, __uint_as_float(p1 << 16), ax);
        ay = fmaf(e1, __uint_as_float(p1 & 0xffff0000u), ay);
        ax = fmaf(e2, __uint_as_float(p2 << 16), ax);
        ay = fmaf(e2, __uint_as_float(p2 & 0xffff0000u), ay);
        ax = fmaf(e3, __uint_as_float(p3 << 16), ax);
        ay = fmaf(e3, __uint_as_float(p3 & 0xffff0000u), ay);
    }
    // fallback for deg > CAP (statistically never: deg ~ Poisson(16))
    for (int j = CAP; j < deg; ++j) {
        int2 st = csr2[beg + j];
        float a = sii + sjv[st.x] + __int_as_float(st.y);
        a = (a > 0.f) ? a : 0.01f * a;
        float e = __expf(fminf(a, 80.f));
        u32 pk = hb[st.x * 32 + hl];
        ax = fmaf(e, __uint_as_float(pk << 16), ax);
        ay = fmaf(e, __uint_as_float(pk & 0xffff0000u), ay);
    }

    if (!active) return;
    float inv = 1.0f / (ssum + 1e-16f);

    if (MODE == 0) {
        float r0 = fmaxf(ax * inv, 0.f);
        float r1 = fmaxf(ay * inv, 0.f);
        houtb[node * 32 + hl] = (u32)f2bf(r0) | ((u32)f2bf(r1) << 16);
    } else {
        float r0 = ax * inv, r1 = ay * inv;
        float l0 = r0 * P[P_CLSW + 4 * hl]     + r1 * P[P_CLSW + 4 * hl + 2];
        float l1 = r0 * P[P_CLSW + 4 * hl + 1] + r1 * P[P_CLSW + 4 * hl + 3];
        #pragma unroll
        for (int o = 16; o > 0; o >>= 1) {
            l0 += __shfl_xor(l0, o);
            l1 += __shfl_xor(l1, o);
        }
        if (hl == 0) {
            l0 += P[P_CLSB];
            l1 += P[P_CLSB + 1];
            if (flag[0]) {
                ((float2*)outp)[node] = make_float2(l0, l1);
            } else {
                ((u32*)outp)[node] = (u32)f2bf(l0) | ((u32)f2bf(l1) << 16);
            }
        }
    }
}

// ---------------------------------------------------------------------------
extern "C" void kernel_launch(void* const* d_in, const int* in_sizes, int n_in,
                              void* d_out, int out_size, void* d_ws, size_t ws_size,
                              hipStream_t stream)
{
    const void* x    = d_in[0];
    const int*  ei   = (const int*)d_in[1];
    const void* et   = d_in[2];
    const void* l1w  = d_in[3];
    const void* l1b  = d_in[4];
    const void* a1w  = d_in[5];
    const void* a1b  = d_in[6];
    const void* t1w  = d_in[7];
    const void* t1b  = d_in[8];
    const void* l2w  = d_in[9];
    const void* l2b  = d_in[10];
    const void* a2w  = d_in[11];
    const void* a2b  = d_in[12];
    const void* t2w  = d_in[13];
    const void* t2b  = d_in[14];
    const void* clsw = d_in[15];
    const void* clsb = d_in[16];

    const int N = in_sizes[0] / 128;
    const int E = in_sizes[2];
    const int nchunks = (E + CH - 1) / CH;   // 391 (<= 512 assumed)
    const int nbkt = (N + 511) >> 9;         // buckets actually used

    char* ws = (char*)d_ws;
    size_t off = 0;
    auto A = [&](size_t bytes) -> char* {
        char* p = ws + off;
        off = (off + bytes + 255) & ~(size_t)255;
        return p;
    };
    int*   flag        = (int*)A(256);
    float* P           = (float*)A(P_TOT * 4);
    u16*   w1fh        = (u16*)A(W1F_ELEMS * 2);
    u16*   w1fl        = (u16*)A(W1F_ELEMS * 2);
    u16*   w2fh        = (u16*)A(W2F_ELEMS * 2);
    u16*   w2fl        = (u16*)A(W2F_ELEMS * 2);
    u32*   h1b         = (u32*)A((size_t)N * 32 * 4);  // bf16 h1; reused as h2
    float* si1         = (float*)A((size_t)N * 4);
    float* sj1         = (float*)A((size_t)N * 4);
    float* si2         = (float*)A((size_t)N * 4);
    float* sj2         = (float*)A((size_t)N * 4);
    int*   chunkhist   = (int*)A((size_t)nchunks * NCHB * 4);
    int*   buckettot   = (int*)A(NCHB * 4);
    int*   bucketstart = (int*)A((size_t)(NCHB + 1) * 4);
    int*   offs        = (int*)A((size_t)(N + 1) * 4);
    int2*  csrA        = (int2*)A((size_t)E * 8);
    int2*  csrB        = (int2*)A((size_t)E * 8);
    char*  unionr      = A((size_t)E * 8 < (size_t)N * 32 * 4
                           ? (size_t)N * 32 * 4 : (size_t)E * 8);
    int2*  staging     = (int2*)unionr;    // sort phase
    u32*   hagb        = (u32*)unionr;     // agg0 bf16 output (after bin)
    (void)ws_size; (void)n_in; (void)out_size;

    detect_dtype<<<1, 256, 0, stream>>>((const u32*)x, 4096, flag);

    prep_params<<<32, 256, 0, stream>>>(l1w, l1b, a1w, a1b, t1w, t1b,
                                        l2w, l2b, a2w, a2b, t2w, t2b,
                                        clsw, clsb, flag, P);

    prep_wfrags<<<(W1F_ELEMS + W2F_ELEMS) / 256, 256, 0, stream>>>(
        P, w1fh, w1fl, w2fh, w2fl);

    node_gemm_mfma<128, 0><<<(N + 63) / 64, 256, 0, stream>>>(
        x, P, P_B1, P_A1W, flag, w1fh, w1fl, h1b, si1, sj1, N);

    count_chunks<<<nchunks, 256, 0, stream>>>(ei + E, chunkhist, E);

    scan_chunks<<<NCHB, 256, 0, stream>>>(chunkhist, buckettot, nchunks);

    bucket_start_scan<<<1, 256, 0, stream>>>(buckettot, bucketstart, offs, N);

    place_chunks<<<nchunks, 256, 0, stream>>>(ei, et, flag, chunkhist,
                                              bucketstart, staging, E);

    bin_edges<<<nbkt, 256, 0, stream>>>(staging, bucketstart, offs, csrA, N);

    temporal_pass<<<(E + 255) / 256, 256, 0, stream>>>(csrA, csrB, P, E);

    aggregate<0><<<(N + 7) / 8, 256, 0, stream>>>(
        offs, csrA, h1b, si1, sj1, P, hagb, nullptr, flag, N);

    node_gemm_mfma<64, 2><<<(N + 63) / 64, 256, 0, stream>>>(
        hagb, P, P_B2, P_A2W, flag, w2fh, w2fl, h1b, si2, sj2, N);

    aggregate<1><<<(N + 7) / 8, 256, 0, stream>>>(
        offs, csrB, h1b, si2, sj2, P, nullptr, d_out, flag, N);
}

// Round 2
// 272.695 us; speedup vs baseline: 1.1922x; 1.0991x over previous
//
#include <hip/hip_runtime.h>

typedef unsigned short u16;
typedef unsigned int u32;

typedef __attribute__((ext_vector_type(8))) short short8v;  // 8 bf16 (4 VGPRs)
typedef __attribute__((ext_vector_type(4))) float float4v;  // 4 f32 acc

__device__ __forceinline__ float bf2f(u16 u) {
    return __uint_as_float(((u32)u) << 16);
}
__device__ __forceinline__ u16 f2bf(float f) {
    u32 u = __float_as_uint(f);
    u32 r = (u + 0x7fffu + ((u >> 16) & 1u)) >> 16;
    return (u16)r;
}
__device__ __forceinline__ float ldf(const void* p, int i, int isf32) {
    return isf32 ? ((const float*)p)[i] : bf2f(((const u16*)p)[i]);
}

// ---- canonical f32 param block offsets (in floats) ----
#define P_W1   0        // 128x64
#define P_W2   8192     // 64x64
#define P_B1   12288    // 64
#define P_B2   12352    // 64
#define P_A1W  12416    // 144
#define P_A1B  12560    // 1
#define P_T1W  12561    // 16
#define P_T1B  12577    // 16
#define P_A2W  12593    // 144
#define P_A2B  12737    // 1
#define P_T2W  12738    // 16
#define P_T2B  12754    // 16
#define P_CLSW 12770    // 128 (64x2)
#define P_CLSB 12898    // 2
#define P_TOT  12900

#define CH   4096       // edges per sort chunk
#define NCHB 256        // padded bucket count; bucket = dst>>9 (<=195)
#define CAP  128        // aggregate per-node LDS cache (max observed deg ~50)

// W-fragment array sizes (u16 elements): (K/32) ksteps * 4 coltiles * 64 lanes * 8
#define W1F_ELEMS 16384   // K=128
#define W2F_ELEMS 8192    // K=64

// ---------------------------------------------------------------------------
// Detect f32 vs bf16 storage of float tensors (round-1 notes).
// ---------------------------------------------------------------------------
__global__ __launch_bounds__(256) void detect_dtype(
    const u32* __restrict__ xw, int nwords, int* __restrict__ flag)
{
    __shared__ int sbad;
    if (threadIdx.x == 0) sbad = 0;
    __syncthreads();
    int bad = 0;
    for (int i = threadIdx.x; i < nwords; i += 256) {
        u32 w = xw[i];
        int ea = (w >> 7) & 0xff;
        if (ea >= 0xF0) bad = 1;
    }
    if (bad) sbad = 1;
    __syncthreads();
    if (threadIdx.x == 0) flag[0] = sbad;
}

// ---------------------------------------------------------------------------
// Convert all small parameter tensors into one f32 param block, AND pack
// W1/W2 into MFMA B-fragment order as bf16 hi/lo pairs (reads raw weights,
// so no dependency on P within this kernel).
// B-frag for mfma_f32_16x16x32_bf16: lane l holds B[k][col] with
// col = ct*16 + (l&15), k = ks*32 + (l>>4)*8 + j  (j = 0..7).
// Memory: idx = (((ks*4 + ct)*64 + l)*8 + j) -> wave loads one uint4/lane.
// ---------------------------------------------------------------------------
__global__ __launch_bounds__(256) void prep_params(
    const void* l1w, const void* l1b, const void* a1w, const void* a1b,
    const void* t1w, const void* t1b, const void* l2w, const void* l2b,
    const void* a2w, const void* a2b, const void* t2w, const void* t2b,
    const void* clsw, const void* clsb,
    const int* __restrict__ flag, float* __restrict__ P,
    u16* __restrict__ w1h, u16* __restrict__ w1l,
    u16* __restrict__ w2h, u16* __restrict__ w2l)
{
    const int f = flag[0];
    const int t = blockIdx.x * 256 + threadIdx.x;
    const int stride = gridDim.x * 256;
#define SEG(src, off, cnt) for (int i = t; i < (cnt); i += stride) P[(off) + i] = ldf(src, i, f)
    SEG(l1w, P_W1, 8192);
    SEG(l2w, P_W2, 4096);
    SEG(l1b, P_B1, 64);
    SEG(l2b, P_B2, 64);
    SEG(a1w, P_A1W, 144);
    SEG(a1b, P_A1B, 1);
    SEG(t1w, P_T1W, 16);
    SEG(t1b, P_T1B, 16);
    SEG(a2w, P_A2W, 144);
    SEG(a2b, P_A2B, 1);
    SEG(t2w, P_T2W, 16);
    SEG(t2b, P_T2B, 16);
    SEG(clsw, P_CLSW, 128);
    SEG(clsb, P_CLSB, 2);
#undef SEG
    // W fragment packing (reads raw weight tensors)
    for (int e = t; e < W1F_ELEMS + W2F_ELEMS; e += stride) {
        int idx;
        const void* wsrc;
        u16 *dh, *dl;
        if (e < W1F_ELEMS) { idx = e; wsrc = l1w; dh = w1h; dl = w1l; }
        else { idx = e - W1F_ELEMS; wsrc = l2w; dh = w2h; dl = w2l; }
        int j = idx & 7;
        int l = (idx >> 3) & 63;
        int ctks = idx >> 9;
        int ct = ctks & 3;
        int ks = ctks >> 2;
        int k = ks * 32 + (l >> 4) * 8 + j;
        int col = ct * 16 + (l & 15);
        float wv = ldf(wsrc, k * 64 + col, f);
        u16 hh = f2bf(wv);
        dh[idx] = hh;
        dl[idx] = f2bf(wv - bf2f(hh));
    }
}

// ---------------------------------------------------------------------------
// Node transform via MFMA: h = x @ W + b (bf16x3 split for f32 accuracy),
// packed bf16 output; fused si/sj. No LDS, no block sync.
// Block = 256 thr = 4 waves; each wave computes a 16-row x 64-col tile.
// XMODE: 0 = runtime flag (f32/bf16 x), 2 = bf16 packed input (layer 2).
// f32 path uses truncation split: hi = top 16 bits (error captured exactly
// by lo), lo = RNE-rounded remainder. Dropped term is lo*lo ~ 2^-17 rel.
// ---------------------------------------------------------------------------
template<int K, int XMODE>
__global__ __launch_bounds__(256) void node_gemm_mfma(
    const void* __restrict__ xin, const float* __restrict__ P,
    int BOFF, int AOFF, const int* __restrict__ flag,
    const u16* __restrict__ wfh, const u16* __restrict__ wfl,
    u32* __restrict__ houtb, float* __restrict__ si, float* __restrict__ sj,
    int nnodes)
{
    const int l = threadIdx.x & 63;
    const int w = threadIdx.x >> 6;
    const int cl = l & 15;          // col-in-tile / A-row lane
    const int cg = l >> 4;          // k-group (loads) / row-group (C)
    const int rowbase = blockIdx.x * 64 + w * 16;
    const bool xf32 = (XMODE == 0) ? (flag[0] != 0) : false;

    const int arow = rowbase + cl;                 // row this lane loads for A
    const int arc = (arow < nnodes) ? arow : 0;    // clamp (stores are guarded)
    const int kb = cg * 8;                         // lane k-offset within 32

    const u16* xb = (const u16*)xin;
    const float* xf = (const float*)xin;
    const short8v* bhp = (const short8v*)wfh;
    const short8v* blp = (const short8v*)wfl;

    float4v acc[4];
    #pragma unroll
    for (int ct = 0; ct < 4; ++ct) acc[ct] = (float4v){0.f, 0.f, 0.f, 0.f};

    #pragma unroll
    for (int ks = 0; ks < K / 32; ++ks) {
        short8v ah, al_;
        bool hasl = false;
        if (XMODE == 2 || !xf32) {
            ah = *(const short8v*)&xb[(size_t)arc * K + ks * 32 + kb];
            al_ = (short8v){0, 0, 0, 0, 0, 0, 0, 0};
        } else {
            float4 v0 = *(const float4*)&xf[(size_t)arc * K + ks * 32 + kb];
            float4 v1 = *(const float4*)&xf[(size_t)arc * K + ks * 32 + kb + 4];
            float fv[8] = { v0.x, v0.y, v0.z, v0.w, v1.x, v1.y, v1.z, v1.w };
            #pragma unroll
            for (int j = 0; j < 8; ++j) {
                u32 u = __float_as_uint(fv[j]);
                ah[j] = (short)(u >> 16);                       // truncated hi
                float hif = __uint_as_float(u & 0xffff0000u);
                al_[j] = (short)f2bf(fv[j] - hif);              // rounded lo
            }
            hasl = true;
        }
        #pragma unroll
        for (int ct = 0; ct < 4; ++ct) {
            short8v bh = bhp[(ks * 4 + ct) * 64 + l];
            short8v bl = blp[(ks * 4 + ct) * 64 + l];
            acc[ct] = __builtin_amdgcn_mfma_f32_16x16x32_bf16(ah, bh, acc[ct], 0, 0, 0);
            acc[ct] = __builtin_amdgcn_mfma_f32_16x16x32_bf16(ah, bl, acc[ct], 0, 0, 0);
            if (hasl)
                acc[ct] = __builtin_amdgcn_mfma_f32_16x16x32_bf16(al_, bh, acc[ct], 0, 0, 0);
        }
    }

    // C layout: lane l holds col = ct*16 + (l&15), row = (l>>4)*4 + r.
    #pragma unroll
    for (int r = 0; r < 4; ++r) {
        int node = rowbase + cg * 4 + r;
        float aiv = 0.f, ajv = 0.f;
        u16 hs[4];
        #pragma unroll
        for (int ct = 0; ct < 4; ++ct) {
            float v = acc[ct][r] + P[BOFF + ct * 16 + cl];
            aiv = fmaf(v, P[AOFF + ct * 16 + cl], aiv);
            ajv = fmaf(v, P[AOFF + 64 + ct * 16 + cl], ajv);
            hs[ct] = f2bf(v);
        }
        #pragma unroll
        for (int o = 1; o < 16; o <<= 1) {
            aiv += __shfl_xor(aiv, o);
            ajv += __shfl_xor(ajv, o);
        }
        if (node < nnodes) {
            u16* hp = (u16*)houtb + (size_t)node * 64 + cl;
            hp[0] = hs[0]; hp[16] = hs[1]; hp[32] = hs[2]; hp[48] = hs[3];
            if (cl == 0) { si[node] = aiv; sj[node] = ajv; }
        }
    }
}

// ---------------------------------------------------------------------------
// Counting sort pass 1: per-chunk bucket histogram (bucket = dst>>9).
// ---------------------------------------------------------------------------
__global__ __launch_bounds__(256) void count_chunks(
    const int* __restrict__ eid, int* __restrict__ chunkhist, int E)
{
    __shared__ int hist[NCHB];
    const int t = threadIdx.x, c = blockIdx.x;
    hist[t] = 0;
    __syncthreads();
    const int base = c * CH;
    #pragma unroll
    for (int i = 0; i < CH / 256; ++i) {
        int e = base + t + i * 256;
        if (e < E) atomicAdd(&hist[eid[e] >> 9], 1);
    }
    __syncthreads();
    chunkhist[c * NCHB + t] = hist[t];
}

// ---------------------------------------------------------------------------
// Scan stage A: one block per bucket; Hillis-Steele over chunk entries.
// ---------------------------------------------------------------------------
__global__ __launch_bounds__(256) void scan_chunks(
    int* __restrict__ chunkhist, int* __restrict__ buckettot, int nchunks)
{
    __shared__ int s[512];
    const int b = blockIdx.x, t = threadIdx.x;
    int v0 = (t < nchunks) ? chunkhist[(size_t)t * NCHB + b] : 0;
    int v1 = (t + 256 < nchunks) ? chunkhist[(size_t)(t + 256) * NCHB + b] : 0;
    s[t] = v0; s[t + 256] = v1;
    __syncthreads();
    for (int off = 1; off < 512; off <<= 1) {
        int x0 = (t >= off) ? s[t - off] : 0;
        int x1 = s[t + 256 - off];
        __syncthreads();
        s[t] += x0; s[t + 256] += x1;
        __syncthreads();
    }
    if (t < nchunks) chunkhist[(size_t)t * NCHB + b] = s[t] - v0;
    if (t + 256 < nchunks) chunkhist[(size_t)(t + 256) * NCHB + b] = s[t + 256] - v1;
    if (t == 255) buckettot[b] = s[511];
}

// ---------------------------------------------------------------------------
// Scan stage B: 1 tiny block. Exclusive scan of bucket totals.
// ---------------------------------------------------------------------------
__global__ __launch_bounds__(256) void bucket_start_scan(
    const int* __restrict__ buckettot, int* __restrict__ bucketstart,
    int* __restrict__ offs, int N)
{
    __shared__ int s[NCHB];
    const int b = threadIdx.x;
    int v = buckettot[b];
    s[b] = v;
    __syncthreads();
    for (int off = 1; off < NCHB; off <<= 1) {
        int x = (b >= off) ? s[b - off] : 0;
        __syncthreads();
        s[b] += x;
        __syncthreads();
    }
    bucketstart[b] = s[b] - v;
    if (b == NCHB - 1) { bucketstart[NCHB] = s[b]; offs[N] = s[b]; }
}

// ---------------------------------------------------------------------------
// Counting sort pass 2: sort each chunk in LDS, coalesced flush to the
// bucket-sorted staging array. Payload (src | ldst<<17, t_bits).
// ---------------------------------------------------------------------------
__global__ __launch_bounds__(256) void place_chunks(
    const int* __restrict__ ei, const void* __restrict__ et,
    const int* __restrict__ flag, const int* __restrict__ chunkhist,
    const int* __restrict__ bucketstart, int2* __restrict__ staging, int E)
{
    __shared__ int2 sorted[CH];            // 32 KB
    __shared__ unsigned char bno[CH];      // 4 KB
    __shared__ int hist[NCHB], lstart[NCHB], cur[NCHB], gb[NCHB];
    const int t = threadIdx.x, c = blockIdx.x;
    const int base = c * CH;
    const int f = flag[0];
    hist[t] = 0;
    gb[t] = bucketstart[t] + chunkhist[c * NCHB + t];
    __syncthreads();
    #pragma unroll
    for (int i = 0; i < CH / 256; ++i) {
        int e = base + t + i * 256;
        if (e < E) atomicAdd(&hist[ei[E + e] >> 9], 1);
    }
    __syncthreads();
    int v = hist[t];
    lstart[t] = v;
    __syncthreads();
    for (int off = 1; off < NCHB; off <<= 1) {
        int x = (t >= off) ? lstart[t - off] : 0;
        __syncthreads();
        lstart[t] += x;
        __syncthreads();
    }
    int ex = lstart[t] - v;   // exclusive local start
    __syncthreads();
    lstart[t] = ex;
    cur[t] = ex;
    __syncthreads();
    #pragma unroll
    for (int i = 0; i < CH / 256; ++i) {
        int e = base + t + i * 256;
        if (e < E) {
            int s_ = ei[e], d = ei[E + e];
            float tt = ldf(et, e, f);
            int b = d >> 9;
            int p = atomicAdd(&cur[b], 1);
            sorted[p] = make_int2(s_ | ((d & 511) << 17), __float_as_int(tt));
            bno[p] = (unsigned char)b;
        }
    }
    __syncthreads();
    const int cnt_tot = min(CH, E - base);
    for (int idx = t; idx < cnt_tot; idx += 256) {
        int b = bno[idx];
        staging[gb[b] + (idx - lstart[b])] = sorted[idx];
    }
}

// ---------------------------------------------------------------------------
// Bin within bucket (low VGPR): per-node LDS histogram + scan -> offs;
// place (src, t_raw) into node-sorted csrA.
// ---------------------------------------------------------------------------
__global__ __launch_bounds__(256) void bin_edges(
    const int2* __restrict__ staging, const int* __restrict__ bucketstart,
    int* __restrict__ offs, int2* __restrict__ csrA, int N)
{
    __shared__ int cnt[512], loc[512];
    const int b = blockIdx.x, t = threadIdx.x;
    const int beg = bucketstart[b], end = bucketstart[b + 1];
    const int nstart = b << 9;
    cnt[t] = 0; cnt[t + 256] = 0;
    __syncthreads();
    for (int i = beg + t; i < end; i += 256)
        atomicAdd(&cnt[(((u32)staging[i].x) >> 17) & 511], 1);
    __syncthreads();
    int v0 = cnt[t], v1 = cnt[t + 256];
    loc[t] = v0; loc[t + 256] = v1;
    __syncthreads();
    for (int off = 1; off < 512; off <<= 1) {
        int x0 = (t >= off) ? loc[t - off] : 0;
        int x1 = loc[t + 256 - off];
        __syncthreads();
        loc[t] += x0; loc[t + 256] += x1;
        __syncthreads();
    }
    int cur0 = beg + loc[t] - v0;
    int cur1 = beg + loc[t + 256] - v1;
    if (nstart + t < N) offs[nstart + t] = cur0;
    if (nstart + t + 256 < N) offs[nstart + t + 256] = cur1;
    cnt[t] = cur0; cnt[t + 256] = cur1;
    __syncthreads();
    for (int i = beg + t; i < end; i += 256) {
        int2 e = staging[i];
        int slot = atomicAdd(&cnt[(((u32)e.x) >> 17) & 511], 1);
        csrA[slot] = make_int2(e.x & 0x1ffff, e.y);
    }
}

// ---------------------------------------------------------------------------
// Aggregate: TWO nodes per wave (half-wave = 32 lanes owns one node).
// Temporal encoding (16-term sin dot) computed INLINE in phase A from raw t
// (replaces the former temporal_pass kernel + csrB buffer): VALU hides under
// the gather latency; the 48 P constants are wave-uniform -> SGPR-hoisted.
// Single alpha pass (bounded alpha, clamp 80 — softmax ratio unchanged).
// LDS cache (src, e) padded to a multiple of 8 with zero-weight entries so
// phase B is ONLY the 8-loads-in-flight group loop (no tail). No block sync
// (cache is wave-private). Global fallback for deg > CAP (never fires).
// ---------------------------------------------------------------------------
template<int MODE>
__global__ __launch_bounds__(256) void aggregate(
    const int* __restrict__ offs, const int2* __restrict__ csr2,
    const u32* __restrict__ hb,
    const float* __restrict__ si, const float* __restrict__ sjv,
    const float* __restrict__ P,
    u32* __restrict__ houtb, void* __restrict__ outp,
    const int* __restrict__ flag, int n)
{
    constexpr int TW = (MODE == 0) ? P_T1W : P_T2W;
    constexpr int TB = (MODE == 0) ? P_T1B : P_T2B;
    constexpr int AW = (MODE == 0) ? P_A1W : P_A2W;
    constexpr int AB = (MODE == 0) ? P_A1B : P_A2B;

    __shared__ int2 cache[4][2][CAP];
    const int wave = threadIdx.x >> 6;
    const int lane = threadIdx.x & 63;
    const int half = lane >> 5;          // which node of the pair
    const int hl = lane & 31;            // lane within half
    const int node = blockIdx.x * 8 + wave * 2 + half;
    const bool active = node < n;
    int beg = 0, end = 0;
    if (active) { beg = offs[node]; end = offs[node + 1]; }
    const int deg = end - beg;
    int2* cw = cache[wave][half];
    const float sii = active ? si[node] : 0.f;

    // phase A: td = sin-encoding dot; e = exp(leaky(si+sj+td)); cache; ssum
    float ssum = 0.f;
    for (int idx = hl; idx < deg; idx += 32) {
        int2 st = csr2[beg + idx];
        float tt = __int_as_float(st.y);
        float td = P[AB];
        #pragma unroll
        for (int k = 0; k < 16; ++k)
            td += __sinf(fmaf(tt, P[TW + k], P[TB + k])) * P[AW + 128 + k];
        float a = sii + sjv[st.x] + td;
        a = (a > 0.f) ? a : 0.01f * a;
        float e = __expf(fminf(a, 80.f));
        if (idx < CAP) cw[idx] = make_int2(st.x, __float_as_int(e));
        ssum += e;
    }
    #pragma unroll
    for (int o = 16; o > 0; o >>= 1) ssum += __shfl_xor(ssum, o);

    // pad cache to a multiple of 8 with zero-weight entries
    const int degc = min(deg, CAP);
    const int degpad = (degc + 7) & ~7;
    if (hl < degpad - degc) cw[degc + hl] = make_int2(0, 0);

    // phase B: 32 lanes per edge row (u32 = 2 bf16 feats); 8 loads in flight
    float ax = 0.f, ay = 0.f;
    for (int j0 = 0; j0 < degpad; j0 += 8) {
        int2 sv[8];
        u32 pv[8];
        #pragma unroll
        for (int q = 0; q < 8; ++q) sv[q] = cw[j0 + q];
        #pragma unroll
        for (int q = 0; q < 8; ++q) pv[q] = hb[sv[q].x * 32 + hl];
        #pragma unroll
        for (int q = 0; q < 8; ++q) {
            float e = __int_as_float(sv[q].y);
            ax = fmaf(e, __uint_as_float(pv[q] << 16), ax);
            ay = fmaf(e, __uint_as_float(pv[q] & 0xffff0000u), ay);
        }
    }
    // fallback for deg > CAP (statistically never: deg ~ Poisson(16))
    for (int j = CAP; j < deg; ++j) {
        int2 st = csr2[beg + j];
        float tt = __int_as_float(st.y);
        float td = P[AB];
        #pragma unroll
        for (int k = 0; k < 16; ++k)
            td += __sinf(fmaf(tt, P[TW + k], P[TB + k])) * P[AW + 128 + k];
        float a = sii + sjv[st.x] + td;
        a = (a > 0.f) ? a : 0.01f * a;
        float e = __expf(fminf(a, 80.f));
        u32 pk = hb[st.x * 32 + hl];
        ax = fmaf(e, __uint_as_float(pk << 16), ax);
        ay = fmaf(e, __uint_as_float(pk & 0xffff0000u), ay);
    }

    if (!active) return;
    float inv = 1.0f / (ssum + 1e-16f);

    if (MODE == 0) {
        float r0 = fmaxf(ax * inv, 0.f);
        float r1 = fmaxf(ay * inv, 0.f);
        houtb[node * 32 + hl] = (u32)f2bf(r0) | ((u32)f2bf(r1) << 16);
    } else {
        float r0 = ax * inv, r1 = ay * inv;
        float l0 = r0 * P[P_CLSW + 4 * hl]     + r1 * P[P_CLSW + 4 * hl + 2];
        float l1 = r0 * P[P_CLSW + 4 * hl + 1] + r1 * P[P_CLSW + 4 * hl + 3];
        #pragma unroll
        for (int o = 16; o > 0; o >>= 1) {
            l0 += __shfl_xor(l0, o);
            l1 += __shfl_xor(l1, o);
        }
        if (hl == 0) {
            l0 += P[P_CLSB];
            l1 += P[P_CLSB + 1];
            if (flag[0]) {
                ((float2*)outp)[node] = make_float2(l0, l1);
            } else {
                ((u32*)outp)[node] = (u32)f2bf(l0) | ((u32)f2bf(l1) << 16);
            }
        }
    }
}

// ---------------------------------------------------------------------------
extern "C" void kernel_launch(void* const* d_in, const int* in_sizes, int n_in,
                              void* d_out, int out_size, void* d_ws, size_t ws_size,
                              hipStream_t stream)
{
    const void* x    = d_in[0];
    const int*  ei   = (const int*)d_in[1];
    const void* et   = d_in[2];
    const void* l1w  = d_in[3];
    const void* l1b  = d_in[4];
    const void* a1w  = d_in[5];
    const void* a1b  = d_in[6];
    const void* t1w  = d_in[7];
    const void* t1b  = d_in[8];
    const void* l2w  = d_in[9];
    const void* l2b  = d_in[10];
    const void* a2w  = d_in[11];
    const void* a2b  = d_in[12];
    const void* t2w  = d_in[13];
    const void* t2b  = d_in[14];
    const void* clsw = d_in[15];
    const void* clsb = d_in[16];

    const int N = in_sizes[0] / 128;
    const int E = in_sizes[2];
    const int nchunks = (E + CH - 1) / CH;   // 391 (<= 512 assumed)
    const int nbkt = (N + 511) >> 9;         // buckets actually used

    char* ws = (char*)d_ws;
    size_t off = 0;
    auto A = [&](size_t bytes) -> char* {
        char* p = ws + off;
        off = (off + bytes + 255) & ~(size_t)255;
        return p;
    };
    int*   flag        = (int*)A(256);
    float* P           = (float*)A(P_TOT * 4);
    u16*   w1fh        = (u16*)A(W1F_ELEMS * 2);
    u16*   w1fl        = (u16*)A(W1F_ELEMS * 2);
    u16*   w2fh        = (u16*)A(W2F_ELEMS * 2);
    u16*   w2fl        = (u16*)A(W2F_ELEMS * 2);
    u32*   h1b         = (u32*)A((size_t)N * 32 * 4);  // bf16 h1; reused as h2
    float* si1         = (float*)A((size_t)N * 4);
    float* sj1         = (float*)A((size_t)N * 4);
    float* si2         = (float*)A((size_t)N * 4);
    float* sj2         = (float*)A((size_t)N * 4);
    int*   chunkhist   = (int*)A((size_t)nchunks * NCHB * 4);
    int*   buckettot   = (int*)A(NCHB * 4);
    int*   bucketstart = (int*)A((size_t)(NCHB + 1) * 4);
    int*   offs        = (int*)A((size_t)(N + 1) * 4);
    int2*  csrA        = (int2*)A((size_t)E * 8);
    char*  unionr      = A((size_t)E * 8 < (size_t)N * 32 * 4
                           ? (size_t)N * 32 * 4 : (size_t)E * 8);
    int2*  staging     = (int2*)unionr;    // sort phase
    u32*   hagb        = (u32*)unionr;     // agg0 bf16 output (after bin)
    (void)ws_size; (void)n_in; (void)out_size;

    detect_dtype<<<1, 256, 0, stream>>>((const u32*)x, 4096, flag);

    prep_params<<<32, 256, 0, stream>>>(l1w, l1b, a1w, a1b, t1w, t1b,
                                        l2w, l2b, a2w, a2b, t2w, t2b,
                                        clsw, clsb, flag, P,
                                        w1fh, w1fl, w2fh, w2fl);

    node_gemm_mfma<128, 0><<<(N + 63) / 64, 256, 0, stream>>>(
        x, P, P_B1, P_A1W, flag, w1fh, w1fl, h1b, si1, sj1, N);

    count_chunks<<<nchunks, 256, 0, stream>>>(ei + E, chunkhist, E);

    scan_chunks<<<NCHB, 256, 0, stream>>>(chunkhist, buckettot, nchunks);

    bucket_start_scan<<<1, 256, 0, stream>>>(buckettot, bucketstart, offs, N);

    place_chunks<<<nchunks, 256, 0, stream>>>(ei, et, flag, chunkhist,
                                              bucketstart, staging, E);

    bin_edges<<<nbkt, 256, 0, stream>>>(staging, bucketstart, offs, csrA, N);

    aggregate<0><<<(N + 7) / 8, 256, 0, stream>>>(
        offs, csrA, h1b, si1, sj1, P, hagb, nullptr, flag, N);

    node_gemm_mfma<64, 2><<<(N + 63) / 64, 256, 0, stream>>>(
        hagb, P, P_B2, P_A2W, flag, w2fh, w2fl, h1b, si2, sj2, N);

    aggregate<1><<<(N + 7) / 8, 256, 0, stream>>>(
        offs, csrA, h1b, si2, sj2, P, nullptr, d_out, flag, N);
}

// Round 3
// 266.890 us; speedup vs baseline: 1.2181x; 1.0218x over previous
//
#include <hip/hip_runtime.h>

typedef unsigned short u16;
typedef unsigned int u32;

typedef __attribute__((ext_vector_type(8))) short short8v;  // 8 bf16 (4 VGPRs)
typedef __attribute__((ext_vector_type(4))) float float4v;  // 4 f32 acc

__device__ __forceinline__ float bf2f(u16 u) {
    return __uint_as_float(((u32)u) << 16);
}
__device__ __forceinline__ u16 f2bf(float f) {
    u32 u = __float_as_uint(f);
    u32 r = (u + 0x7fffu + ((u >> 16) & 1u)) >> 16;
    return (u16)r;
}
__device__ __forceinline__ float ldf(const void* p, int i, int isf32) {
    return isf32 ? ((const float*)p)[i] : bf2f(((const u16*)p)[i]);
}

// ---- canonical f32 param block offsets (in floats) ----
#define P_W1   0        // 128x64
#define P_W2   8192     // 64x64
#define P_B1   12288    // 64
#define P_B2   12352    // 64
#define P_A1W  12416    // 144
#define P_A1B  12560    // 1
#define P_T1W  12561    // 16
#define P_T1B  12577    // 16
#define P_A2W  12593    // 144
#define P_A2B  12737    // 1
#define P_T2W  12738    // 16
#define P_T2B  12754    // 16
#define P_CLSW 12770    // 128 (64x2)
#define P_CLSB 12898    // 2
#define P_TOT  12900

#define CH   4096       // edges per sort chunk
#define NCHB 256        // padded bucket count; bucket = dst>>9 (<=195)
#define CAP  128        // aggregate per-node LDS cache (max observed deg ~50)

// W-fragment array sizes (u16 elements): (K/32) ksteps * 4 coltiles * 64 lanes * 8
#define W1F_ELEMS 16384   // K=128
#define W2F_ELEMS 8192    // K=64

// ---------------------------------------------------------------------------
// FUSED: prep_params (+inline dtype detect) and count_chunks in one launch.
// Blocks [0, nchunks): per-chunk bucket histogram (bucket = dst>>9).
// Blocks [nchunks, nchunks+32): param conversion + W-fragment packing; each
// prep block recomputes the dtype flag locally (16 KB redundant read).
// ---------------------------------------------------------------------------
__global__ __launch_bounds__(256) void prep_and_count(
    const u32* __restrict__ xw,
    const void* l1w, const void* l1b, const void* a1w, const void* a1b,
    const void* t1w, const void* t1b, const void* l2w, const void* l2b,
    const void* a2w, const void* a2b, const void* t2w, const void* t2b,
    const void* clsw, const void* clsb,
    int* __restrict__ flag, float* __restrict__ P,
    u16* __restrict__ w1h, u16* __restrict__ w1l,
    u16* __restrict__ w2h, u16* __restrict__ w2l,
    const int* __restrict__ eid, int* __restrict__ chunkhist,
    int E, int nchunks)
{
    if ((int)blockIdx.x < nchunks) {
        // ---- count_chunks body ----
        __shared__ int hist[NCHB];
        const int t = threadIdx.x, c = blockIdx.x;
        hist[t] = 0;
        __syncthreads();
        const int base = c * CH;
        #pragma unroll
        for (int i = 0; i < CH / 256; ++i) {
            int e = base + t + i * 256;
            if (e < E) atomicAdd(&hist[eid[e] >> 9], 1);
        }
        __syncthreads();
        chunkhist[c * NCHB + t] = hist[t];
        return;
    }

    // ---- prep body (32 blocks) ----
    const int bid = blockIdx.x - nchunks;
    __shared__ int sbad;
    if (threadIdx.x == 0) sbad = 0;
    __syncthreads();
    int bad = 0;
    for (int i = threadIdx.x; i < 4096; i += 256) {
        u32 w = xw[i];
        int ea = (w >> 7) & 0xff;
        if (ea >= 0xF0) bad = 1;
    }
    if (bad) sbad = 1;
    __syncthreads();
    const int f = sbad;
    if (bid == 0 && threadIdx.x == 0) flag[0] = f;

    const int t = bid * 256 + threadIdx.x;
    const int stride = 32 * 256;
#define SEG(src, off, cnt) for (int i = t; i < (cnt); i += stride) P[(off) + i] = ldf(src, i, f)
    SEG(l1w, P_W1, 8192);
    SEG(l2w, P_W2, 4096);
    SEG(l1b, P_B1, 64);
    SEG(l2b, P_B2, 64);
    SEG(a1w, P_A1W, 144);
    SEG(a1b, P_A1B, 1);
    SEG(t1w, P_T1W, 16);
    SEG(t1b, P_T1B, 16);
    SEG(a2w, P_A2W, 144);
    SEG(a2b, P_A2B, 1);
    SEG(t2w, P_T2W, 16);
    SEG(t2b, P_T2B, 16);
    SEG(clsw, P_CLSW, 128);
    SEG(clsb, P_CLSB, 2);
#undef SEG
    // W fragment packing (reads raw weight tensors).
    // B-frag for mfma_f32_16x16x32_bf16: lane l holds B[k][col] with
    // col = ct*16 + (l&15), k = ks*32 + (l>>4)*8 + j (j=0..7).
    // Memory: idx = (((ks*4+ct)*64 + l)*8 + j) -> wave loads one uint4/lane.
    for (int e = t; e < W1F_ELEMS + W2F_ELEMS; e += stride) {
        int idx;
        const void* wsrc;
        u16 *dh, *dl;
        if (e < W1F_ELEMS) { idx = e; wsrc = l1w; dh = w1h; dl = w1l; }
        else { idx = e - W1F_ELEMS; wsrc = l2w; dh = w2h; dl = w2l; }
        int j = idx & 7;
        int l = (idx >> 3) & 63;
        int ctks = idx >> 9;
        int ct = ctks & 3;
        int ks = ctks >> 2;
        int k = ks * 32 + (l >> 4) * 8 + j;
        int col = ct * 16 + (l & 15);
        float wv = ldf(wsrc, k * 64 + col, f);
        u16 hh = f2bf(wv);
        dh[idx] = hh;
        dl[idx] = f2bf(wv - bf2f(hh));
    }
}

// ---------------------------------------------------------------------------
// Node transform via MFMA (device body): h = x @ W + b (bf16x3 split),
// packed bf16 output; fused si/sj. No LDS, no block sync.
// Each wave computes a 16-row x 64-col tile.
// XMODE: 0 = runtime flag (f32/bf16 x), 2 = bf16 packed input (layer 2).
// f32 path uses truncation split: hi = top 16 bits, lo = RNE remainder.
// ---------------------------------------------------------------------------
template<int K, int XMODE>
__device__ __forceinline__ void gemm_body(
    int bid, const void* __restrict__ xin, const float* __restrict__ P,
    int BOFF, int AOFF, const int* __restrict__ flag,
    const u16* __restrict__ wfh, const u16* __restrict__ wfl,
    u32* __restrict__ houtb, float* __restrict__ si, float* __restrict__ sj,
    int nnodes)
{
    const int l = threadIdx.x & 63;
    const int w = threadIdx.x >> 6;
    const int cl = l & 15;          // col-in-tile / A-row lane
    const int cg = l >> 4;          // k-group (loads) / row-group (C)
    const int rowbase = bid * 64 + w * 16;
    const bool xf32 = (XMODE == 0) ? (flag[0] != 0) : false;

    const int arow = rowbase + cl;                 // row this lane loads for A
    const int arc = (arow < nnodes) ? arow : 0;    // clamp (stores are guarded)
    const int kb = cg * 8;                         // lane k-offset within 32

    const u16* xb = (const u16*)xin;
    const float* xf = (const float*)xin;
    const short8v* bhp = (const short8v*)wfh;
    const short8v* blp = (const short8v*)wfl;

    float4v acc[4];
    #pragma unroll
    for (int ct = 0; ct < 4; ++ct) acc[ct] = (float4v){0.f, 0.f, 0.f, 0.f};

    #pragma unroll
    for (int ks = 0; ks < K / 32; ++ks) {
        short8v ah, al_;
        bool hasl = false;
        if (XMODE == 2 || !xf32) {
            ah = *(const short8v*)&xb[(size_t)arc * K + ks * 32 + kb];
            al_ = (short8v){0, 0, 0, 0, 0, 0, 0, 0};
        } else {
            float4 v0 = *(const float4*)&xf[(size_t)arc * K + ks * 32 + kb];
            float4 v1 = *(const float4*)&xf[(size_t)arc * K + ks * 32 + kb + 4];
            float fv[8] = { v0.x, v0.y, v0.z, v0.w, v1.x, v1.y, v1.z, v1.w };
            #pragma unroll
            for (int j = 0; j < 8; ++j) {
                u32 u = __float_as_uint(fv[j]);
                ah[j] = (short)(u >> 16);                       // truncated hi
                float hif = __uint_as_float(u & 0xffff0000u);
                al_[j] = (short)f2bf(fv[j] - hif);              // rounded lo
            }
            hasl = true;
        }
        #pragma unroll
        for (int ct = 0; ct < 4; ++ct) {
            short8v bh = bhp[(ks * 4 + ct) * 64 + l];
            short8v bl = blp[(ks * 4 + ct) * 64 + l];
            acc[ct] = __builtin_amdgcn_mfma_f32_16x16x32_bf16(ah, bh, acc[ct], 0, 0, 0);
            acc[ct] = __builtin_amdgcn_mfma_f32_16x16x32_bf16(ah, bl, acc[ct], 0, 0, 0);
            if (hasl)
                acc[ct] = __builtin_amdgcn_mfma_f32_16x16x32_bf16(al_, bh, acc[ct], 0, 0, 0);
        }
    }

    // C layout: lane l holds col = ct*16 + (l&15), row = (l>>4)*4 + r.
    #pragma unroll
    for (int r = 0; r < 4; ++r) {
        int node = rowbase + cg * 4 + r;
        float aiv = 0.f, ajv = 0.f;
        u16 hs[4];
        #pragma unroll
        for (int ct = 0; ct < 4; ++ct) {
            float v = acc[ct][r] + P[BOFF + ct * 16 + cl];
            aiv = fmaf(v, P[AOFF + ct * 16 + cl], aiv);
            ajv = fmaf(v, P[AOFF + 64 + ct * 16 + cl], ajv);
            hs[ct] = f2bf(v);
        }
        #pragma unroll
        for (int o = 1; o < 16; o <<= 1) {
            aiv += __shfl_xor(aiv, o);
            ajv += __shfl_xor(ajv, o);
        }
        if (node < nnodes) {
            u16* hp = (u16*)houtb + (size_t)node * 64 + cl;
            hp[0] = hs[0]; hp[16] = hs[1]; hp[32] = hs[2]; hp[48] = hs[3];
            if (cl == 0) { si[node] = aiv; sj[node] = ajv; }
        }
    }
}

// ---------------------------------------------------------------------------
// Scan stage A (device body): one block per bucket; Hillis-Steele over
// chunk entries -> exclusive chunk offsets + bucket totals.
// ---------------------------------------------------------------------------
__device__ __forceinline__ void scan_body(
    int b, int* __restrict__ chunkhist, int* __restrict__ buckettot,
    int nchunks)
{
    __shared__ int s[512];
    const int t = threadIdx.x;
    int v0 = (t < nchunks) ? chunkhist[(size_t)t * NCHB + b] : 0;
    int v1 = (t + 256 < nchunks) ? chunkhist[(size_t)(t + 256) * NCHB + b] : 0;
    s[t] = v0; s[t + 256] = v1;
    __syncthreads();
    for (int off = 1; off < 512; off <<= 1) {
        int x0 = (t >= off) ? s[t - off] : 0;
        int x1 = s[t + 256 - off];
        __syncthreads();
        s[t] += x0; s[t + 256] += x1;
        __syncthreads();
    }
    if (t < nchunks) chunkhist[(size_t)t * NCHB + b] = s[t] - v0;
    if (t + 256 < nchunks) chunkhist[(size_t)(t + 256) * NCHB + b] = s[t + 256] - v1;
    if (t == 255) buckettot[b] = s[511];
}

// ---------------------------------------------------------------------------
// FUSED: scan_chunks (blocks [0,NCHB)) + layer-1 GEMM (remaining blocks).
// Independent work; single launch removes a dispatch gap and overlaps the
// tiny scan with the GEMM.
// ---------------------------------------------------------------------------
__global__ __launch_bounds__(256) void scan_and_gemm1(
    int* __restrict__ chunkhist, int* __restrict__ buckettot, int nchunks,
    const void* __restrict__ x, const float* __restrict__ P,
    const int* __restrict__ flag,
    const u16* __restrict__ w1h, const u16* __restrict__ w1l,
    u32* __restrict__ h1b, float* __restrict__ si1, float* __restrict__ sj1,
    int N)
{
    if (blockIdx.x < NCHB) {
        scan_body(blockIdx.x, chunkhist, buckettot, nchunks);
        return;
    }
    gemm_body<128, 0>(blockIdx.x - NCHB, x, P, P_B1, P_A1W, flag,
                      w1h, w1l, h1b, si1, sj1, N);
}

// ---------------------------------------------------------------------------
// Standalone layer-2 GEMM.
// ---------------------------------------------------------------------------
__global__ __launch_bounds__(256) void node_gemm2(
    const void* __restrict__ xin, const float* __restrict__ P,
    const int* __restrict__ flag,
    const u16* __restrict__ wfh, const u16* __restrict__ wfl,
    u32* __restrict__ houtb, float* __restrict__ si, float* __restrict__ sj,
    int nnodes)
{
    gemm_body<64, 2>(blockIdx.x, xin, P, P_B2, P_A2W, flag,
                     wfh, wfl, houtb, si, sj, nnodes);
}

// ---------------------------------------------------------------------------
// Counting sort pass 2: sort each chunk in LDS, coalesced flush to the
// bucket-sorted staging array. Payload (src | ldst<<17, t_bits).
// Bucket starts computed locally from buckettot (replaces the former
// bucket_start_scan kernel): one extra 256-wide LDS scan per block.
// ---------------------------------------------------------------------------
__global__ __launch_bounds__(256) void place_chunks(
    const int* __restrict__ ei, const void* __restrict__ et,
    const int* __restrict__ flag, const int* __restrict__ chunkhist,
    const int* __restrict__ buckettot, int2* __restrict__ staging, int E)
{
    __shared__ int2 sorted[CH];            // 32 KB
    __shared__ unsigned char bno[CH];      // 4 KB
    __shared__ int hist[NCHB], lstart[NCHB], cur[NCHB], gb[NCHB], bs[NCHB];
    const int t = threadIdx.x, c = blockIdx.x;
    const int base = c * CH;
    const int f = flag[0];

    // local exclusive scan of bucket totals -> bucket starts
    int bv = buckettot[t];
    bs[t] = bv;
    hist[t] = 0;
    __syncthreads();
    for (int off = 1; off < NCHB; off <<= 1) {
        int x = (t >= off) ? bs[t - off] : 0;
        __syncthreads();
        bs[t] += x;
        __syncthreads();
    }
    gb[t] = (bs[t] - bv) + chunkhist[c * NCHB + t];
    __syncthreads();

    #pragma unroll
    for (int i = 0; i < CH / 256; ++i) {
        int e = base + t + i * 256;
        if (e < E) atomicAdd(&hist[ei[E + e] >> 9], 1);
    }
    __syncthreads();
    int v = hist[t];
    lstart[t] = v;
    __syncthreads();
    for (int off = 1; off < NCHB; off <<= 1) {
        int x = (t >= off) ? lstart[t - off] : 0;
        __syncthreads();
        lstart[t] += x;
        __syncthreads();
    }
    int ex = lstart[t] - v;   // exclusive local start
    __syncthreads();
    lstart[t] = ex;
    cur[t] = ex;
    __syncthreads();
    #pragma unroll
    for (int i = 0; i < CH / 256; ++i) {
        int e = base + t + i * 256;
        if (e < E) {
            int s_ = ei[e], d = ei[E + e];
            float tt = ldf(et, e, f);
            int b = d >> 9;
            int p = atomicAdd(&cur[b], 1);
            sorted[p] = make_int2(s_ | ((d & 511) << 17), __float_as_int(tt));
            bno[p] = (unsigned char)b;
        }
    }
    __syncthreads();
    const int cnt_tot = min(CH, E - base);
    for (int idx = t; idx < cnt_tot; idx += 256) {
        int b = bno[idx];
        staging[gb[b] + (idx - lstart[b])] = sorted[idx];
    }
}

// ---------------------------------------------------------------------------
// Bin within bucket (low VGPR): per-node LDS histogram + scan -> offs;
// place (src, t_raw) into node-sorted csrA. Bucket range computed locally
// from buckettot (local 256-scan).
// ---------------------------------------------------------------------------
__global__ __launch_bounds__(256) void bin_edges(
    const int2* __restrict__ staging, const int* __restrict__ buckettot,
    int* __restrict__ offs, int2* __restrict__ csrA, int N, int E)
{
    __shared__ int cnt[512], loc[512], bs[NCHB];
    const int b = blockIdx.x, t = threadIdx.x;

    int bv = buckettot[t];
    bs[t] = bv;
    cnt[t] = 0; cnt[t + 256] = 0;
    __syncthreads();
    for (int off = 1; off < NCHB; off <<= 1) {
        int x = (t >= off) ? bs[t - off] : 0;
        __syncthreads();
        bs[t] += x;
        __syncthreads();
    }
    const int end = bs[b];
    const int beg = (b == 0) ? 0 : bs[b - 1];
    if (b == 0 && t == 0) offs[N] = E;
    const int nstart = b << 9;
    __syncthreads();

    for (int i = beg + t; i < end; i += 256)
        atomicAdd(&cnt[(((u32)staging[i].x) >> 17) & 511], 1);
    __syncthreads();
    int v0 = cnt[t], v1 = cnt[t + 256];
    loc[t] = v0; loc[t + 256] = v1;
    __syncthreads();
    for (int off = 1; off < 512; off <<= 1) {
        int x0 = (t >= off) ? loc[t - off] : 0;
        int x1 = loc[t + 256 - off];
        __syncthreads();
        loc[t] += x0; loc[t + 256] += x1;
        __syncthreads();
    }
    int cur0 = beg + loc[t] - v0;
    int cur1 = beg + loc[t + 256] - v1;
    if (nstart + t < N) offs[nstart + t] = cur0;
    if (nstart + t + 256 < N) offs[nstart + t + 256] = cur1;
    cnt[t] = cur0; cnt[t + 256] = cur1;
    __syncthreads();
    for (int i = beg + t; i < end; i += 256) {
        int2 e = staging[i];
        int slot = atomicAdd(&cnt[(((u32)e.x) >> 17) & 511], 1);
        csrA[slot] = make_int2(e.x & 0x1ffff, e.y);
    }
}

// ---------------------------------------------------------------------------
// Aggregate: FOUR nodes per wave (16 lanes own one node; lane ql covers
// feats 4ql..4ql+3 via one uint2 = 8 B gather). Halves load-instruction
// count per gathered byte vs the 32-lane version and doubles per-lane MLP.
// Temporal encoding (16-term sin dot) inline in phase A. Single alpha pass
// (bounded alpha, clamp 80 — softmax ratio unchanged). LDS cache (src, e)
// padded to a multiple of 8 with zero-weight entries so phase B is ONLY the
// 8-loads-in-flight group loop. No block sync (cache is quarter-private).
// Global fallback for deg > CAP (never fires: deg ~ Poisson(16)).
// ---------------------------------------------------------------------------
template<int MODE>
__global__ __launch_bounds__(256) void aggregate(
    const int* __restrict__ offs, const int2* __restrict__ csr2,
    const u32* __restrict__ hb,
    const float* __restrict__ si, const float* __restrict__ sjv,
    const float* __restrict__ P,
    u32* __restrict__ houtb, void* __restrict__ outp,
    const int* __restrict__ flag, int n)
{
    constexpr int TW = (MODE == 0) ? P_T1W : P_T2W;
    constexpr int TB = (MODE == 0) ? P_T1B : P_T2B;
    constexpr int AW = (MODE == 0) ? P_A1W : P_A2W;
    constexpr int AB = (MODE == 0) ? P_A1B : P_A2B;

    __shared__ int2 cache[4][4][CAP];    // 16 KB
    const int wave = threadIdx.x >> 6;
    const int lane = threadIdx.x & 63;
    const int q = lane >> 4;             // which node of the four
    const int ql = lane & 15;            // lane within quarter
    const int node = blockIdx.x * 16 + wave * 4 + q;
    const bool active = node < n;
    int beg = 0, end = 0;
    if (active) { beg = offs[node]; end = offs[node + 1]; }
    const int deg = end - beg;
    int2* cw = cache[wave][q];
    const float sii = active ? si[node] : 0.f;

    // phase A: td = sin-encoding dot; e = exp(leaky(si+sj+td)); cache; ssum
    float ssum = 0.f;
    for (int idx = ql; idx < deg; idx += 16) {
        int2 st = csr2[beg + idx];
        float tt = __int_as_float(st.y);
        float td = P[AB];
        #pragma unroll
        for (int k = 0; k < 16; ++k)
            td += __sinf(fmaf(tt, P[TW + k], P[TB + k])) * P[AW + 128 + k];
        float a = sii + sjv[st.x] + td;
        a = (a > 0.f) ? a : 0.01f * a;
        float e = __expf(fminf(a, 80.f));
        if (idx < CAP) cw[idx] = make_int2(st.x, __float_as_int(e));
        ssum += e;
    }
    #pragma unroll
    for (int o = 8; o > 0; o >>= 1) ssum += __shfl_xor(ssum, o);

    // pad cache to a multiple of 8 with zero-weight entries
    const int degc = min(deg, CAP);
    const int degpad = (degc + 7) & ~7;
    if (ql < degpad - degc) cw[degc + ql] = make_int2(0, 0);

    // phase B: 16 lanes per edge row (uint2 = 4 bf16 feats); 8 in flight
    const uint2* hb2 = (const uint2*)hb;
    float a0 = 0.f, a1 = 0.f, a2 = 0.f, a3 = 0.f;
    for (int j0 = 0; j0 < degpad; j0 += 8) {
        int2 sv[8];
        uint2 pv[8];
        #pragma unroll
        for (int p = 0; p < 8; ++p) sv[p] = cw[j0 + p];
        #pragma unroll
        for (int p = 0; p < 8; ++p) pv[p] = hb2[sv[p].x * 16 + ql];
        #pragma unroll
        for (int p = 0; p < 8; ++p) {
            float e = __int_as_float(sv[p].y);
            a0 = fmaf(e, __uint_as_float(pv[p].x << 16), a0);
            a1 = fmaf(e, __uint_as_float(pv[p].x & 0xffff0000u), a1);
            a2 = fmaf(e, __uint_as_float(pv[p].y << 16), a2);
            a3 = fmaf(e, __uint_as_float(pv[p].y & 0xffff0000u), a3);
        }
    }
    // fallback for deg > CAP (statistically never)
    for (int j = CAP; j < deg; ++j) {
        int2 st = csr2[beg + j];
        float tt = __int_as_float(st.y);
        float td = P[AB];
        #pragma unroll
        for (int k = 0; k < 16; ++k)
            td += __sinf(fmaf(tt, P[TW + k], P[TB + k])) * P[AW + 128 + k];
        float a = sii + sjv[st.x] + td;
        a = (a > 0.f) ? a : 0.01f * a;
        float e = __expf(fminf(a, 80.f));
        uint2 pk = hb2[st.x * 16 + ql];
        a0 = fmaf(e, __uint_as_float(pk.x << 16), a0);
        a1 = fmaf(e, __uint_as_float(pk.x & 0xffff0000u), a1);
        a2 = fmaf(e, __uint_as_float(pk.y << 16), a2);
        a3 = fmaf(e, __uint_as_float(pk.y & 0xffff0000u), a3);
    }

    if (!active) return;
    float inv = 1.0f / (ssum + 1e-16f);

    if (MODE == 0) {
        float r0 = fmaxf(a0 * inv, 0.f);
        float r1 = fmaxf(a1 * inv, 0.f);
        float r2 = fmaxf(a2 * inv, 0.f);
        float r3 = fmaxf(a3 * inv, 0.f);
        u32 w0 = (u32)f2bf(r0) | ((u32)f2bf(r1) << 16);
        u32 w1 = (u32)f2bf(r2) | ((u32)f2bf(r3) << 16);
        *(uint2*)&houtb[node * 32 + 2 * ql] = make_uint2(w0, w1);
    } else {
        float r0 = a0 * inv, r1 = a1 * inv, r2 = a2 * inv, r3 = a3 * inv;
        const int f0 = 4 * ql;
        float l0 = r0 * P[P_CLSW + 2 * f0]     + r1 * P[P_CLSW + 2 * f0 + 2]
                 + r2 * P[P_CLSW + 2 * f0 + 4] + r3 * P[P_CLSW + 2 * f0 + 6];
        float l1 = r0 * P[P_CLSW + 2 * f0 + 1] + r1 * P[P_CLSW + 2 * f0 + 3]
                 + r2 * P[P_CLSW + 2 * f0 + 5] + r3 * P[P_CLSW + 2 * f0 + 7];
        #pragma unroll
        for (int o = 8; o > 0; o >>= 1) {
            l0 += __shfl_xor(l0, o);
            l1 += __shfl_xor(l1, o);
        }
        if (ql == 0) {
            l0 += P[P_CLSB];
            l1 += P[P_CLSB + 1];
            if (flag[0]) {
                ((float2*)outp)[node] = make_float2(l0, l1);
            } else {
                ((u32*)outp)[node] = (u32)f2bf(l0) | ((u32)f2bf(l1) << 16);
            }
        }
    }
}

// ---------------------------------------------------------------------------
extern "C" void kernel_launch(void* const* d_in, const int* in_sizes, int n_in,
                              void* d_out, int out_size, void* d_ws, size_t ws_size,
                              hipStream_t stream)
{
    const void* x    = d_in[0];
    const int*  ei   = (const int*)d_in[1];
    const void* et   = d_in[2];
    const void* l1w  = d_in[3];
    const void* l1b  = d_in[4];
    const void* a1w  = d_in[5];
    const void* a1b  = d_in[6];
    const void* t1w  = d_in[7];
    const void* t1b  = d_in[8];
    const void* l2w  = d_in[9];
    const void* l2b  = d_in[10];
    const void* a2w  = d_in[11];
    const void* a2b  = d_in[12];
    const void* t2w  = d_in[13];
    const void* t2b  = d_in[14];
    const void* clsw = d_in[15];
    const void* clsb = d_in[16];

    const int N = in_sizes[0] / 128;
    const int E = in_sizes[2];
    const int nchunks = (E + CH - 1) / CH;   // 391 (<= 512 assumed)
    const int nbkt = (N + 511) >> 9;         // buckets actually used
    const int gblocks = (N + 63) / 64;

    char* ws = (char*)d_ws;
    size_t off = 0;
    auto A = [&](size_t bytes) -> char* {
        char* p = ws + off;
        off = (off + bytes + 255) & ~(size_t)255;
        return p;
    };
    int*   flag        = (int*)A(256);
    float* P           = (float*)A(P_TOT * 4);
    u16*   w1fh        = (u16*)A(W1F_ELEMS * 2);
    u16*   w1fl        = (u16*)A(W1F_ELEMS * 2);
    u16*   w2fh        = (u16*)A(W2F_ELEMS * 2);
    u16*   w2fl        = (u16*)A(W2F_ELEMS * 2);
    u32*   h1b         = (u32*)A((size_t)N * 32 * 4);  // bf16 h1; reused as h2
    float* si1         = (float*)A((size_t)N * 4);
    float* sj1         = (float*)A((size_t)N * 4);
    float* si2         = (float*)A((size_t)N * 4);
    float* sj2         = (float*)A((size_t)N * 4);
    int*   chunkhist   = (int*)A((size_t)nchunks * NCHB * 4);
    int*   buckettot   = (int*)A(NCHB * 4);
    int*   offs        = (int*)A((size_t)(N + 1) * 4);
    int2*  csrA        = (int2*)A((size_t)E * 8);
    char*  unionr      = A((size_t)E * 8 < (size_t)N * 32 * 4
                           ? (size_t)N * 32 * 4 : (size_t)E * 8);
    int2*  staging     = (int2*)unionr;    // sort phase
    u32*   hagb        = (u32*)unionr;     // agg0 bf16 output (after bin)
    (void)ws_size; (void)n_in; (void)out_size;

    prep_and_count<<<nchunks + 32, 256, 0, stream>>>(
        (const u32*)x, l1w, l1b, a1w, a1b, t1w, t1b,
        l2w, l2b, a2w, a2b, t2w, t2b, clsw, clsb,
        flag, P, w1fh, w1fl, w2fh, w2fl,
        ei + E, chunkhist, E, nchunks);

    scan_and_gemm1<<<NCHB + gblocks, 256, 0, stream>>>(
        chunkhist, buckettot, nchunks,
        x, P, flag, w1fh, w1fl, h1b, si1, sj1, N);

    place_chunks<<<nchunks, 256, 0, stream>>>(ei, et, flag, chunkhist,
                                              buckettot, staging, E);

    bin_edges<<<nbkt, 256, 0, stream>>>(staging, buckettot, offs, csrA, N, E);

    aggregate<0><<<(N + 15) / 16, 256, 0, stream>>>(
        offs, csrA, h1b, si1, sj1, P, hagb, nullptr, flag, N);

    node_gemm2<<<gblocks, 256, 0, stream>>>(
        hagb, P, flag, w2fh, w2fl, h1b, si2, sj2, N);

    aggregate<1><<<(N + 15) / 16, 256, 0, stream>>>(
        offs, csrA, h1b, si2, sj2, P, nullptr, d_out, flag, N);
}